// Round 3
// baseline (1048.392 us; speedup 1.0000x reference)
//
#include <hip/hip_runtime.h>

// MoE top-2: N=8192, D=1024, E=8, DFF=4096.
// Inputs/outputs are FP32 storage (per reference dtypes); MFMA internals bf16.
// gate -> scan -> assign -> convert x -> 2x{convtrans w1 quad -> gemm1+SiLU}
//   -> 2x{convtrans w2 quad -> gemm2 + weighted atomicAdd into fp32 d_out}.
// Workspace: 177 MiB (routing 1 + xb 16 + H 128 + rotating wt 32).

#define N_TOK 8192
#define DIM   1024
#define NE    8
#define DFF   4096
#define BM 128
#define BN 128
#define BK 64
#define QE 4   // experts per rotating weight-quad

typedef unsigned short u16;
typedef short bf16x8 __attribute__((ext_vector_type(8)));
typedef float f32x4  __attribute__((ext_vector_type(4)));

// ---- workspace offsets (bytes) ----
#define TOKE_OFF   0u            // int[8192]
#define TOKW_OFF   32768u        // float[8192]
#define TLIST_OFF  65536u        // int[16384]
#define WLIST_OFF  131072u       // float[16384]
#define COUNTS_OFF 196608u       // int[8]
#define BASEP_OFF  196672u       // int[8]
#define CURSOR_OFF 196736u       // int[8]
#define XB_OFF     1048576u      // 16 MiB: bf16 x [8192][1024]
#define H_OFF      17825792u     // 128 MiB: bf16 H [16384][4096]
#define WT_OFF     152043520u    // 32 MiB: rotating bf16 transposed weight quad
// total = 177 MiB

__device__ __forceinline__ float bf2f(u16 h) {
    return __uint_as_float(((unsigned)h) << 16);
}
__device__ __forceinline__ u16 f2bf(float f) {
    unsigned u = __float_as_uint(f);
    unsigned r = u + 0x7FFFu + ((u >> 16) & 1u);   // RNE
    return (u16)(r >> 16);
}

// ---------------- convert x: fp32 -> bf16 ---------------------------------
__global__ void convert_x(const float* __restrict__ x, u16* __restrict__ xb) {
    int idx = (blockIdx.x * 256 + threadIdx.x) * 4;
    float4 v = *(const float4*)&x[idx];
    ushort4 o;
    o.x = f2bf(v.x); o.y = f2bf(v.y); o.z = f2bf(v.z); o.w = f2bf(v.w);
    *(ushort4*)&xb[idx] = o;
}

// ------ convert+transpose: in fp32 [z][R][C] -> out bf16 [z][C][R] --------
__global__ void convtrans(const float* __restrict__ in, u16* __restrict__ out,
                          int R, int C) {
    __shared__ float tile[32][33];
    int z = blockIdx.z;
    const float* src = in  + (size_t)z * R * C;
    u16*         dst = out + (size_t)z * R * C;
    int c0 = blockIdx.x * 32, r0 = blockIdx.y * 32;
    int tx = threadIdx.x & 31, ty = threadIdx.x >> 5;   // 32 x 8
#pragma unroll
    for (int i = 0; i < 32; i += 8)
        tile[ty + i][tx] = src[(size_t)(r0 + ty + i) * C + c0 + tx];
    __syncthreads();
#pragma unroll
    for (int i = 0; i < 32; i += 8)
        dst[(size_t)(c0 + ty + i) * R + r0 + tx] = f2bf(tile[tx][ty + i]);
}

// ---------------- gate: one wave per token, top-2 + counts ----------------
__global__ void gate_kernel(const float* __restrict__ x, const float* __restrict__ gw,
                            int* __restrict__ tok_e, float* __restrict__ tok_w,
                            int* __restrict__ counts) {
    __shared__ float gsm[NE * DIM];        // [e][d], 32 KiB
    int t = blockIdx.x, lane = threadIdx.x;
    for (int i = lane; i < NE * DIM; i += 64) {
        int d = i >> 3, e = i & 7;         // gw is [d][e]
        gsm[e * DIM + d] = gw[i];
    }
    __syncthreads();
    float acc[NE];
#pragma unroll
    for (int e = 0; e < NE; ++e) acc[e] = 0.f;
    const float* xr = x + (size_t)t * DIM;
    for (int i = lane; i < DIM; i += 64) {
        float xv = xr[i];
#pragma unroll
        for (int e = 0; e < NE; ++e) acc[e] += xv * gsm[e * DIM + i];
    }
#pragma unroll
    for (int off = 32; off > 0; off >>= 1) {
#pragma unroll
        for (int e = 0; e < NE; ++e) acc[e] += __shfl_xor(acc[e], off, 64);
    }
    if (lane == 0) {
        int a = 0;
#pragma unroll
        for (int e = 1; e < NE; ++e) if (acc[e] > acc[a]) a = e;   // ties -> lowest
        int b = (a == 0) ? 1 : 0;
#pragma unroll
        for (int e = 0; e < NE; ++e) if (e != a && acc[e] > acc[b]) b = e;
        // renormalized top-2 softmax == 2-way softmax of the top-2 logits
        float wa = 1.f / (1.f + __expf(acc[b] - acc[a]));
        tok_e[t] = (a << 3) | b;
        tok_w[t] = wa;
        atomicAdd(&counts[a], 1);
        atomicAdd(&counts[b], 1);
    }
}

__global__ void scan_kernel(const int* __restrict__ counts, int* __restrict__ basep,
                            int* __restrict__ cursor) {
    if (threadIdx.x == 0) {
        int s = 0;
        for (int e = 0; e < NE; ++e) { basep[e] = s; s += counts[e]; cursor[e] = 0; }
    }
}

__global__ void assign_kernel(const int* __restrict__ tok_e, const float* __restrict__ tok_w,
                              const int* __restrict__ basep, int* __restrict__ cursor,
                              int* __restrict__ tlist, float* __restrict__ wlist) {
    int t = blockIdx.x * 256 + threadIdx.x;
    if (t >= N_TOK) return;
    int ee = tok_e[t];
    int a = ee >> 3, b = ee & 7;
    float wa = tok_w[t];
    int pa = atomicAdd(&cursor[a], 1);
    int sa = basep[a] + pa;
    tlist[sa] = t;  wlist[sa] = wa;
    int pb = atomicAdd(&cursor[b], 1);
    int sb = basep[b] + pb;
    tlist[sb] = t;  wlist[sb] = 1.f - wa;
}

// ---------------- gemm1+SiLU: H[slot][f] = silu(xb[tok] @ w1[e]) ----------
// w1t = QE experts of w1 transposed to [f][d], bf16. 128x128 tile, BK=64.
__global__ __launch_bounds__(256) void gemm1_silu(
        const u16* __restrict__ xb, const u16* __restrict__ w1t,
        const int* __restrict__ tlist, const int* __restrict__ counts,
        const int* __restrict__ basep, u16* __restrict__ H, int ebase) {
    int bx = blockIdx.x;
    int le = bx >> 11;           // 0..QE-1  (64 mt * 32 nt = 2048 per expert)
    int e  = ebase + le;
    int mt = (bx >> 5) & 63;
    int nt = bx & 31;
    int cnt = counts[e];
    int row0 = mt * BM;
    if (row0 >= cnt) return;
    int nv = cnt - row0; if (nv > BM) nv = BM;
    int gb = basep[e] + row0;    // global slot base of this tile

    __shared__ __align__(16) u16 As[BM * BK];   // 16 KiB, [m][swizzled k]
    __shared__ __align__(16) u16 Bs[BN * BK];

    int tid = threadIdx.x;
    int lane = tid & 63, wid = tid >> 6;
    int wm = (wid & 1) * 64, wn = (wid >> 1) * 64;

    int srow = tid >> 3;         // staging rows srow + i*32, 8-bf16 chunk skc
    int skc  = tid & 7;
    const u16* aptr[4];
#pragma unroll
    for (int i = 0; i < 4; ++i) {
        int r = srow + i * 32;
        int rr = (r < nv) ? r : 0;
        aptr[i] = xb + (size_t)tlist[gb + rr] * DIM + skc * 8;
    }
    const u16* bptr = w1t + ((size_t)le * DFF + (size_t)nt * BN + srow) * DIM + skc * 8;

    f32x4 acc[4][4];
#pragma unroll
    for (int i = 0; i < 4; ++i)
#pragma unroll
        for (int j = 0; j < 4; ++j) acc[i][j] = (f32x4){0.f, 0.f, 0.f, 0.f};

    for (int k0 = 0; k0 < DIM; k0 += BK) {
#pragma unroll
        for (int i = 0; i < 4; ++i) {
            int r = srow + i * 32;
            *(uint4*)&As[(r * 8 + (skc ^ (r & 7))) * 8] = *(const uint4*)(aptr[i] + k0);
            *(uint4*)&Bs[(r * 8 + (skc ^ (r & 7))) * 8] =
                *(const uint4*)(bptr + (size_t)i * 32 * DIM + k0);
        }
        __syncthreads();
#pragma unroll
        for (int ks = 0; ks < 2; ++ks) {
            int kc = ks * 4 + (lane >> 4);
            bf16x8 af[4], bfr[4];
#pragma unroll
            for (int mi = 0; mi < 4; ++mi) {
                int r = wm + mi * 16 + (lane & 15);
                af[mi] = *(const bf16x8*)&As[(r * 8 + (kc ^ (r & 7))) * 8];
            }
#pragma unroll
            for (int ni = 0; ni < 4; ++ni) {
                int r = wn + ni * 16 + (lane & 15);
                bfr[ni] = *(const bf16x8*)&Bs[(r * 8 + (kc ^ (r & 7))) * 8];
            }
#pragma unroll
            for (int mi = 0; mi < 4; ++mi)
#pragma unroll
                for (int ni = 0; ni < 4; ++ni)
                    acc[mi][ni] = __builtin_amdgcn_mfma_f32_16x16x32_bf16(
                        af[mi], bfr[ni], acc[mi][ni], 0, 0, 0);
        }
        __syncthreads();
    }
    // epilogue: SiLU -> bf16 -> H. C layout: col=lane&15, row=(lane>>4)*4+r.
#pragma unroll
    for (int mi = 0; mi < 4; ++mi) {
#pragma unroll
        for (int r = 0; r < 4; ++r) {
            int row = wm + mi * 16 + (lane >> 4) * 4 + r;
            if (row < nv) {
                size_t ho = (size_t)(gb + row) * DFF + nt * BN + wn + (lane & 15);
#pragma unroll
                for (int ni = 0; ni < 4; ++ni) {
                    float v = acc[mi][ni][r];
                    H[ho + ni * 16] = f2bf(v / (1.f + __expf(-v)));
                }
            }
        }
    }
}

// ---- gemm2 + combine: y[tok][d] += w * (H[slot] @ w2[e]), fp32 atomics ----
// w2t = QE experts of w2 transposed to [d][f], bf16.
__global__ __launch_bounds__(256) void gemm2_combine(
        const u16* __restrict__ H, const u16* __restrict__ w2t,
        const int* __restrict__ tlist, const float* __restrict__ wlist,
        const int* __restrict__ counts, const int* __restrict__ basep,
        float* __restrict__ y, int ebase) {
    int bx = blockIdx.x;
    int le = bx >> 9;            // 0..QE-1  (64 mt * 8 nt = 512 per expert)
    int e  = ebase + le;
    int mt = (bx >> 3) & 63;
    int nt = bx & 7;
    int cnt = counts[e];
    int row0 = mt * BM;
    if (row0 >= cnt) return;
    int nv = cnt - row0; if (nv > BM) nv = BM;
    int gb = basep[e] + row0;

    __shared__ __align__(16) u16 As[BM * BK];
    __shared__ __align__(16) u16 Bs[BN * BK];

    int tid = threadIdx.x;
    int lane = tid & 63, wid = tid >> 6;
    int wm = (wid & 1) * 64, wn = (wid >> 1) * 64;

    int srow = tid >> 3;
    int skc  = tid & 7;
    const u16* aptr[4];
#pragma unroll
    for (int i = 0; i < 4; ++i) {
        int r = srow + i * 32;
        int rr = (r < nv) ? r : 0;
        aptr[i] = H + (size_t)(gb + rr) * DFF + skc * 8;
    }
    const u16* bptr = w2t + ((size_t)le * DIM + (size_t)nt * BN + srow) * DFF + skc * 8;

    f32x4 acc[4][4];
#pragma unroll
    for (int i = 0; i < 4; ++i)
#pragma unroll
        for (int j = 0; j < 4; ++j) acc[i][j] = (f32x4){0.f, 0.f, 0.f, 0.f};

    for (int k0 = 0; k0 < DFF; k0 += BK) {
#pragma unroll
        for (int i = 0; i < 4; ++i) {
            int r = srow + i * 32;
            *(uint4*)&As[(r * 8 + (skc ^ (r & 7))) * 8] = *(const uint4*)(aptr[i] + k0);
            *(uint4*)&Bs[(r * 8 + (skc ^ (r & 7))) * 8] =
                *(const uint4*)(bptr + (size_t)i * 32 * DFF + k0);
        }
        __syncthreads();
#pragma unroll
        for (int ks = 0; ks < 2; ++ks) {
            int kc = ks * 4 + (lane >> 4);
            bf16x8 af[4], bfr[4];
#pragma unroll
            for (int mi = 0; mi < 4; ++mi) {
                int r = wm + mi * 16 + (lane & 15);
                af[mi] = *(const bf16x8*)&As[(r * 8 + (kc ^ (r & 7))) * 8];
            }
#pragma unroll
            for (int ni = 0; ni < 4; ++ni) {
                int r = wn + ni * 16 + (lane & 15);
                bfr[ni] = *(const bf16x8*)&Bs[(r * 8 + (kc ^ (r & 7))) * 8];
            }
#pragma unroll
            for (int mi = 0; mi < 4; ++mi)
#pragma unroll
                for (int ni = 0; ni < 4; ++ni)
                    acc[mi][ni] = __builtin_amdgcn_mfma_f32_16x16x32_bf16(
                        af[mi], bfr[ni], acc[mi][ni], 0, 0, 0);
        }
        __syncthreads();
    }
#pragma unroll
    for (int mi = 0; mi < 4; ++mi) {
#pragma unroll
        for (int r = 0; r < 4; ++r) {
            int row = wm + mi * 16 + (lane >> 4) * 4 + r;
            if (row < nv) {
                int gslot = gb + row;
                int t = tlist[gslot];
                float w = wlist[gslot];
                size_t yo = (size_t)t * DIM + nt * BN + wn + (lane & 15);
#pragma unroll
                for (int ni = 0; ni < 4; ++ni)
                    atomicAdd(&y[yo + ni * 16], w * acc[mi][ni][r]);
            }
        }
    }
}

extern "C" void kernel_launch(void* const* d_in, const int* in_sizes, int n_in,
                              void* d_out, int out_size, void* d_ws, size_t ws_size,
                              hipStream_t stream) {
    const float* x  = (const float*)d_in[0];   // [N, D] fp32
    const float* gw = (const float*)d_in[1];   // [D, E] fp32
    const float* w1 = (const float*)d_in[2];   // [E, D, DFF] fp32
    const float* w2 = (const float*)d_in[3];   // [E, DFF, D] fp32
    float* y = (float*)d_out;                  // [N, D] fp32

    char* ws = (char*)d_ws;
    int*   tok_e  = (int*)(ws + TOKE_OFF);
    float* tok_w  = (float*)(ws + TOKW_OFF);
    int*   tlist  = (int*)(ws + TLIST_OFF);
    float* wlist  = (float*)(ws + WLIST_OFF);
    int*   counts = (int*)(ws + COUNTS_OFF);
    int*   basep  = (int*)(ws + BASEP_OFF);
    int*   cursor = (int*)(ws + CURSOR_OFF);
    u16*   xb     = (u16*)(ws + XB_OFF);
    u16*   H      = (u16*)(ws + H_OFF);
    u16*   wt     = (u16*)(ws + WT_OFF);       // rotating transposed-weight quad

    hipMemsetAsync(counts, 0, 32, stream);
    hipMemsetAsync(y, 0, (size_t)N_TOK * DIM * sizeof(float), stream);
    convert_x<<<N_TOK * DIM / 1024, 256, 0, stream>>>(x, xb);
    gate_kernel<<<N_TOK, 64, 0, stream>>>(x, gw, tok_e, tok_w, counts);
    scan_kernel<<<1, 64, 0, stream>>>(counts, basep, cursor);
    assign_kernel<<<N_TOK / 256, 256, 0, stream>>>(tok_e, tok_w, basep, cursor, tlist, wlist);
    for (int q = 0; q < NE / QE; ++q) {
        // w1 quad [QE][DIM][DFF] fp32 -> wt [QE][DFF][DIM] bf16
        convtrans<<<dim3(DFF / 32, DIM / 32, QE), 256, 0, stream>>>(
            w1 + (size_t)q * QE * DIM * DFF, wt, DIM, DFF);
        gemm1_silu<<<QE * 64 * 32, 256, 0, stream>>>(xb, wt, tlist, counts, basep, H, q * QE);
    }
    for (int q = 0; q < NE / QE; ++q) {
        // w2 quad [QE][DFF][DIM] fp32 -> wt [QE][DIM][DFF] bf16
        convtrans<<<dim3(DIM / 32, DFF / 32, QE), 256, 0, stream>>>(
            w2 + (size_t)q * QE * DFF * DIM, wt, DFF, DIM);
        gemm2_combine<<<QE * 64 * 8, 256, 0, stream>>>(H, wt, tlist, wlist, counts, basep,
                                                       y, q * QE);
    }
}

// Round 4
// 989.767 us; speedup vs baseline: 1.0592x; 1.0592x over previous
//
#include <hip/hip_runtime.h>

// MoE top-2: N=8192, D=1024, E=8, DFF=4096. FP32 storage, bf16 MFMA internals.
// gate(+x->bf16 fuse) -> scan -> assign -> 2x{convtrans w1 -> gemm1+SiLU}
//   -> 2x{convtrans w2 -> gemm2 + weighted atomicAdd into fp32 d_out}.
// GEMM staging via global_load_lds dwordx4 (async, swizzle moved to global addr).

#define N_TOK 8192
#define DIM   1024
#define NE    8
#define DFF   4096
#define BM 128
#define BN 128
#define BK 64
#define QE 4   // experts per rotating weight-quad

typedef unsigned short u16;
typedef short bf16x8 __attribute__((ext_vector_type(8)));
typedef float f32x4  __attribute__((ext_vector_type(4)));

// ---- workspace offsets (bytes) ----
#define TOKE_OFF   0u            // int[8192]
#define TOKW_OFF   32768u        // float[8192]
#define TLIST_OFF  65536u        // int[16384]
#define WLIST_OFF  131072u       // float[16384]
#define COUNTS_OFF 196608u       // int[8]
#define BASEP_OFF  196672u       // int[8]
#define CURSOR_OFF 196736u       // int[8]
#define XB_OFF     1048576u      // 16 MiB: bf16 x [8192][1024]
#define H_OFF      17825792u     // 128 MiB: bf16 H [16384][4096]
#define WT_OFF     152043520u    // 32 MiB: rotating bf16 transposed weight quad
// total = 177 MiB

__device__ __forceinline__ float bf2f(u16 h) {
    return __uint_as_float(((unsigned)h) << 16);
}
__device__ __forceinline__ u16 f2bf(float f) {
    unsigned u = __float_as_uint(f);
    unsigned r = u + 0x7FFFu + ((u >> 16) & 1u);   // RNE
    return (u16)(r >> 16);
}

#define GLL16(g, l)                                                             \
    __builtin_amdgcn_global_load_lds(                                           \
        (const __attribute__((address_space(1))) unsigned int*)(g),             \
        (__attribute__((address_space(3))) unsigned int*)(l), 16, 0, 0)

// ------ convert+transpose: in fp32 [z][R][C] -> out bf16 [z][C][R] --------
__global__ void convtrans(const float* __restrict__ in, u16* __restrict__ out,
                          int R, int C) {
    __shared__ float tile[32][33];
    int z = blockIdx.z;
    const float* src = in  + (size_t)z * R * C;
    u16*         dst = out + (size_t)z * R * C;
    int c0 = blockIdx.x * 32, r0 = blockIdx.y * 32;
    int tx = threadIdx.x & 31, ty = threadIdx.x >> 5;   // 32 x 8
#pragma unroll
    for (int i = 0; i < 32; i += 8)
        tile[ty + i][tx] = src[(size_t)(r0 + ty + i) * C + c0 + tx];
    __syncthreads();
#pragma unroll
    for (int i = 0; i < 32; i += 8)
        dst[(size_t)(c0 + ty + i) * R + r0 + tx] = f2bf(tile[tx][ty + i]);
}

// ------ gate: 256 thr/block, 8 tokens/wave; fuses x fp32->bf16 conversion --
__global__ __launch_bounds__(256) void gate_kernel(
        const float* __restrict__ x, const float* __restrict__ gw,
        u16* __restrict__ xb, int* __restrict__ tok_e, float* __restrict__ tok_w,
        int* __restrict__ counts) {
    __shared__ float gsm[NE * DIM];        // [e][d], 32 KiB
    __shared__ int hcnt[NE];
    int tid = threadIdx.x;
    if (tid < NE) hcnt[tid] = 0;
    for (int i = tid; i < NE * DIM; i += 256) {
        int d = i >> 3, e = i & 7;         // gw is [d][e]
        gsm[e * DIM + d] = gw[i];
    }
    __syncthreads();
    int lane = tid & 63, wid = tid >> 6;
    int t0 = blockIdx.x * 32 + wid * 8;
    for (int tt = 0; tt < 8; ++tt) {
        int t = t0 + tt;
        const float4* xr  = (const float4*)(x  + (size_t)t * DIM);
        ushort4*      xbr = (ushort4*)(xb + (size_t)t * DIM);
        float acc[NE];
#pragma unroll
        for (int e = 0; e < NE; ++e) acc[e] = 0.f;
#pragma unroll
        for (int j = 0; j < 4; ++j) {
            float4 xv = xr[j * 64 + lane];
            ushort4 o;
            o.x = f2bf(xv.x); o.y = f2bf(xv.y); o.z = f2bf(xv.z); o.w = f2bf(xv.w);
            xbr[j * 64 + lane] = o;
            int dbase = (j * 64 + lane) * 4;
#pragma unroll
            for (int e = 0; e < NE; ++e) {
                float4 g = *(const float4*)&gsm[e * DIM + dbase];
                acc[e] += xv.x * g.x + xv.y * g.y + xv.z * g.z + xv.w * g.w;
            }
        }
#pragma unroll
        for (int off = 32; off > 0; off >>= 1) {
#pragma unroll
            for (int e = 0; e < NE; ++e) acc[e] += __shfl_xor(acc[e], off, 64);
        }
        if (lane == 0) {
            int a = 0;
#pragma unroll
            for (int e = 1; e < NE; ++e) if (acc[e] > acc[a]) a = e;   // ties -> lowest
            int b = (a == 0) ? 1 : 0;
#pragma unroll
            for (int e = 0; e < NE; ++e) if (e != a && acc[e] > acc[b]) b = e;
            // renormalized top-2 softmax == 2-way softmax of the top-2 logits
            float wa = 1.f / (1.f + __expf(acc[b] - acc[a]));
            tok_e[t] = (a << 3) | b;
            tok_w[t] = wa;
            atomicAdd(&hcnt[a], 1);
            atomicAdd(&hcnt[b], 1);
        }
    }
    __syncthreads();
    if (tid < NE) atomicAdd(&counts[tid], hcnt[tid]);
}

__global__ void scan_kernel(const int* __restrict__ counts, int* __restrict__ basep,
                            int* __restrict__ cursor) {
    if (threadIdx.x == 0) {
        int s = 0;
        for (int e = 0; e < NE; ++e) { basep[e] = s; s += counts[e]; cursor[e] = 0; }
    }
}

__global__ void assign_kernel(const int* __restrict__ tok_e, const float* __restrict__ tok_w,
                              const int* __restrict__ basep, int* __restrict__ cursor,
                              int* __restrict__ tlist, float* __restrict__ wlist) {
    int t = blockIdx.x * 256 + threadIdx.x;
    if (t >= N_TOK) return;
    int ee = tok_e[t];
    int a = ee >> 3, b = ee & 7;
    float wa = tok_w[t];
    int pa = atomicAdd(&cursor[a], 1);
    int sa = basep[a] + pa;
    tlist[sa] = t;  wlist[sa] = wa;
    int pb = atomicAdd(&cursor[b], 1);
    int sb = basep[b] + pb;
    tlist[sb] = t;  wlist[sb] = 1.f - wa;
}

// ---------------- gemm1+SiLU: H[slot][f] = silu(xb[tok] @ w1[e]) ----------
// w1t = QE experts of [f][d] bf16. 128x128 tile, BK=64, async LDS staging.
__global__ __launch_bounds__(256) void gemm1_silu(
        const u16* __restrict__ xb, const u16* __restrict__ w1t,
        const int* __restrict__ tlist, const int* __restrict__ counts,
        const int* __restrict__ basep, u16* __restrict__ H, int ebase) {
    int bx = blockIdx.x;
    int le = bx >> 11;           // 0..QE-1  (64 mt * 32 nt = 2048 per expert)
    int e  = ebase + le;
    int mt = (bx >> 5) & 63;
    int nt = bx & 31;
    int cnt = counts[e];
    int row0 = mt * BM;
    if (row0 >= cnt) return;
    int nv = cnt - row0; if (nv > BM) nv = BM;
    int gb = basep[e] + row0;

    __shared__ __align__(16) u16 As[BM * BK];   // 16 KiB each
    __shared__ __align__(16) u16 Bs[BN * BK];

    int tid = threadIdx.x;
    int lane = tid & 63, wid = tid >> 6;
    int wm = (wid & 1) * 64, wn = (wid >> 1) * 64;

    // async staging: wave issues 4 A + 4 B global_load_lds dwordx4 per K-iter.
    // LDS layout forced to chunkidx = ldsbase/16 + lane; XOR swizzle applied to
    // the GLOBAL source chunk so fragment reads keep the conflict-free pattern.
    const u16* ga[4]; const u16* gbp[4]; int loff[4];
#pragma unroll
    for (int i = 0; i < 4; ++i) {
        int cidx = (wid * 4 + i) * 64 + lane;   // 0..1023
        int row = cidx >> 3;
        int cg  = (cidx & 7) ^ (row & 7);
        int ra  = (row < nv) ? row : 0;
        ga[i]  = xb + (size_t)tlist[gb + ra] * DIM + cg * 8;
        gbp[i] = w1t + ((size_t)le * DFF + (size_t)nt * BN + row) * DIM + cg * 8;
        loff[i] = (wid * 4 + i) * 512;          // u16 elements (1 KiB)
    }

    f32x4 acc[4][4];
#pragma unroll
    for (int i = 0; i < 4; ++i)
#pragma unroll
        for (int j = 0; j < 4; ++j) acc[i][j] = (f32x4){0.f, 0.f, 0.f, 0.f};

    for (int k0 = 0; k0 < DIM; k0 += BK) {
#pragma unroll
        for (int i = 0; i < 4; ++i) {
            GLL16(ga[i] + k0, &As[loff[i]]);
            GLL16(gbp[i] + k0, &Bs[loff[i]]);
        }
        __syncthreads();
#pragma unroll
        for (int ks = 0; ks < 2; ++ks) {
            int kc = ks * 4 + (lane >> 4);
            bf16x8 af[4], bfr[4];
#pragma unroll
            for (int mi = 0; mi < 4; ++mi) {
                int r = wm + mi * 16 + (lane & 15);
                af[mi] = *(const bf16x8*)&As[(r * 8 + (kc ^ (r & 7))) * 8];
            }
#pragma unroll
            for (int ni = 0; ni < 4; ++ni) {
                int r = wn + ni * 16 + (lane & 15);
                bfr[ni] = *(const bf16x8*)&Bs[(r * 8 + (kc ^ (r & 7))) * 8];
            }
#pragma unroll
            for (int mi = 0; mi < 4; ++mi)
#pragma unroll
                for (int ni = 0; ni < 4; ++ni)
                    acc[mi][ni] = __builtin_amdgcn_mfma_f32_16x16x32_bf16(
                        af[mi], bfr[ni], acc[mi][ni], 0, 0, 0);
        }
        __syncthreads();
    }
    // epilogue: SiLU -> bf16 -> H. C layout: col=lane&15, row=(lane>>4)*4+r.
#pragma unroll
    for (int mi = 0; mi < 4; ++mi) {
#pragma unroll
        for (int r = 0; r < 4; ++r) {
            int row = wm + mi * 16 + (lane >> 4) * 4 + r;
            if (row < nv) {
                size_t ho = (size_t)(gb + row) * DFF + nt * BN + wn + (lane & 15);
#pragma unroll
                for (int ni = 0; ni < 4; ++ni) {
                    float v = acc[mi][ni][r];
                    H[ho + ni * 16] = f2bf(v / (1.f + __expf(-v)));
                }
            }
        }
    }
}

// ---- gemm2 + combine: y[tok][d] += w * (H[slot] @ w2[e]), fp32 atomics ----
// w2t = QE experts of [d][f] bf16.
__global__ __launch_bounds__(256) void gemm2_combine(
        const u16* __restrict__ H, const u16* __restrict__ w2t,
        const int* __restrict__ tlist, const float* __restrict__ wlist,
        const int* __restrict__ counts, const int* __restrict__ basep,
        float* __restrict__ y, int ebase) {
    int bx = blockIdx.x;
    int le = bx >> 9;            // 0..QE-1  (64 mt * 8 nt = 512 per expert)
    int e  = ebase + le;
    int mt = (bx >> 3) & 63;
    int nt = bx & 7;
    int cnt = counts[e];
    int row0 = mt * BM;
    if (row0 >= cnt) return;
    int nv = cnt - row0; if (nv > BM) nv = BM;
    int gb = basep[e] + row0;

    __shared__ __align__(16) u16 As[BM * BK];
    __shared__ __align__(16) u16 Bs[BN * BK];

    int tid = threadIdx.x;
    int lane = tid & 63, wid = tid >> 6;
    int wm = (wid & 1) * 64, wn = (wid >> 1) * 64;

    const u16* ga[4]; const u16* gbp[4]; int loff[4];
#pragma unroll
    for (int i = 0; i < 4; ++i) {
        int cidx = (wid * 4 + i) * 64 + lane;
        int row = cidx >> 3;
        int cg  = (cidx & 7) ^ (row & 7);
        int ra  = (row < nv) ? row : 0;
        ga[i]  = H + (size_t)(gb + ra) * DFF + cg * 8;
        gbp[i] = w2t + ((size_t)le * DIM + (size_t)nt * BN + row) * DFF + cg * 8;
        loff[i] = (wid * 4 + i) * 512;
    }

    f32x4 acc[4][4];
#pragma unroll
    for (int i = 0; i < 4; ++i)
#pragma unroll
        for (int j = 0; j < 4; ++j) acc[i][j] = (f32x4){0.f, 0.f, 0.f, 0.f};

    for (int k0 = 0; k0 < DFF; k0 += BK) {
#pragma unroll
        for (int i = 0; i < 4; ++i) {
            GLL16(ga[i] + k0, &As[loff[i]]);
            GLL16(gbp[i] + k0, &Bs[loff[i]]);
        }
        __syncthreads();
#pragma unroll
        for (int ks = 0; ks < 2; ++ks) {
            int kc = ks * 4 + (lane >> 4);
            bf16x8 af[4], bfr[4];
#pragma unroll
            for (int mi = 0; mi < 4; ++mi) {
                int r = wm + mi * 16 + (lane & 15);
                af[mi] = *(const bf16x8*)&As[(r * 8 + (kc ^ (r & 7))) * 8];
            }
#pragma unroll
            for (int ni = 0; ni < 4; ++ni) {
                int r = wn + ni * 16 + (lane & 15);
                bfr[ni] = *(const bf16x8*)&Bs[(r * 8 + (kc ^ (r & 7))) * 8];
            }
#pragma unroll
            for (int mi = 0; mi < 4; ++mi)
#pragma unroll
                for (int ni = 0; ni < 4; ++ni)
                    acc[mi][ni] = __builtin_amdgcn_mfma_f32_16x16x32_bf16(
                        af[mi], bfr[ni], acc[mi][ni], 0, 0, 0);
        }
        __syncthreads();
    }
#pragma unroll
    for (int mi = 0; mi < 4; ++mi) {
#pragma unroll
        for (int r = 0; r < 4; ++r) {
            int row = wm + mi * 16 + (lane >> 4) * 4 + r;
            if (row < nv) {
                int gslot = gb + row;
                int t = tlist[gslot];
                float w = wlist[gslot];
                size_t yo = (size_t)t * DIM + nt * BN + wn + (lane & 15);
#pragma unroll
                for (int ni = 0; ni < 4; ++ni)
                    atomicAdd(&y[yo + ni * 16], w * acc[mi][ni][r]);
            }
        }
    }
}

extern "C" void kernel_launch(void* const* d_in, const int* in_sizes, int n_in,
                              void* d_out, int out_size, void* d_ws, size_t ws_size,
                              hipStream_t stream) {
    const float* x  = (const float*)d_in[0];   // [N, D] fp32
    const float* gw = (const float*)d_in[1];   // [D, E] fp32
    const float* w1 = (const float*)d_in[2];   // [E, D, DFF] fp32
    const float* w2 = (const float*)d_in[3];   // [E, DFF, D] fp32
    float* y = (float*)d_out;                  // [N, D] fp32

    char* ws = (char*)d_ws;
    int*   tok_e  = (int*)(ws + TOKE_OFF);
    float* tok_w  = (float*)(ws + TOKW_OFF);
    int*   tlist  = (int*)(ws + TLIST_OFF);
    float* wlist  = (float*)(ws + WLIST_OFF);
    int*   counts = (int*)(ws + COUNTS_OFF);
    int*   basep  = (int*)(ws + BASEP_OFF);
    int*   cursor = (int*)(ws + CURSOR_OFF);
    u16*   xb     = (u16*)(ws + XB_OFF);
    u16*   H      = (u16*)(ws + H_OFF);
    u16*   wt     = (u16*)(ws + WT_OFF);

    hipMemsetAsync(counts, 0, 32, stream);
    hipMemsetAsync(y, 0, (size_t)N_TOK * DIM * sizeof(float), stream);
    gate_kernel<<<N_TOK / 32, 256, 0, stream>>>(x, gw, xb, tok_e, tok_w, counts);
    scan_kernel<<<1, 64, 0, stream>>>(counts, basep, cursor);
    assign_kernel<<<N_TOK / 256, 256, 0, stream>>>(tok_e, tok_w, basep, cursor, tlist, wlist);
    for (int q = 0; q < NE / QE; ++q) {
        convtrans<<<dim3(DFF / 32, DIM / 32, QE), 256, 0, stream>>>(
            w1 + (size_t)q * QE * DIM * DFF, wt, DIM, DFF);
        gemm1_silu<<<QE * 64 * 32, 256, 0, stream>>>(xb, wt, tlist, counts, basep, H, q * QE);
    }
    for (int q = 0; q < NE / QE; ++q) {
        convtrans<<<dim3(DIM / 32, DFF / 32, QE), 256, 0, stream>>>(
            w2 + (size_t)q * QE * DFF * DIM, wt, DFF, DIM);
        gemm2_combine<<<QE * 64 * 8, 256, 0, stream>>>(H, wt, tlist, wlist, counts, basep,
                                                       y, q * QE);
    }
}